// Round 2
// baseline (3211.802 us; speedup 1.0000x reference)
//
#include <hip/hip_runtime.h>

#define DMM 768
#define DFF 3072
#define NH  12
#define HD  64
#define SQ  197
#define BA  64
#define NDD 732
#define MROWS (BA*SQ)   // 12608
#define MPAD  12672     // 99*128

typedef unsigned short u16;
typedef __bf16 bf16x8 __attribute__((ext_vector_type(8)));
typedef float  f32x4  __attribute__((ext_vector_type(4)));
typedef unsigned short us8 __attribute__((ext_vector_type(8)));

__device__ __forceinline__ float b2f(u16 u) {
    unsigned v = ((unsigned)u) << 16;
    float f; __builtin_memcpy(&f, &v, 4); return f;
}
__device__ __forceinline__ u16 f2b(float f) {
    unsigned v; __builtin_memcpy(&v, &f, 4);
    unsigned r = v + 0x7FFFu + ((v >> 16) & 1u);
    return (u16)(r >> 16);
}
__device__ __forceinline__ float gelu_exact(float x) {
    return 0.5f * x * (1.0f + erff(x * 0.70710678118654752f));
}

// ---------------- patch embed: x[B,14,14,DM] fp32 + cls -> h fp32 ---------
__global__ void patch_k(const float* __restrict__ x, const float* __restrict__ cls,
                        float* __restrict__ h) {
    long idx = (long)blockIdx.x * 256 + threadIdx.x;
    if (idx >= (long)MPAD * DMM) return;
    long r = idx / DMM; int c = (int)(idx % DMM);
    float v = 0.0f;
    if (r < MROWS) {
        int b = (int)(r / SQ), s = (int)(r % SQ);
        v = (s == 0) ? cls[c] : x[((long)b * 196 + (s - 1)) * DMM + c];
    }
    h[idx] = v;
}

// ---------------- final copy fp32 h -> fp32 out ---------------------------
__global__ void out_k(const float* __restrict__ h, float* __restrict__ out) {
    long idx = (long)blockIdx.x * 256 + threadIdx.x;
    if (idx < (long)MROWS * DMM) out[idx] = h[idx];
}

// ------- fused transpose+cast: in fp32 [K][N] -> out bf16 [N][K] ----------
__global__ __launch_bounds__(256) void tcast_k(const float* __restrict__ in,
                                               u16* __restrict__ out,
                                               int Kd, int Nd) {
    __shared__ float t[32][33];
    int k0 = blockIdx.x * 32, n0 = blockIdx.y * 32;
    int tx = threadIdx.x & 31, ty = threadIdx.x >> 5;   // ty 0..7
    #pragma unroll
    for (int i = 0; i < 4; ++i)
        t[tx][ty + 8 * i] = in[(long)(k0 + ty + 8 * i) * Nd + n0 + tx];
    __syncthreads();
    #pragma unroll
    for (int i = 0; i < 4; ++i)
        out[(long)(n0 + ty + 8 * i) * Kd + k0 + tx] = f2b(t[ty + 8 * i][tx]);
}

// ---------------- layernorm: h fp32 -> hn bf16 ----------------------------
__global__ __launch_bounds__(256) void ln_k(const float* __restrict__ h,
                                            const float* __restrict__ g,
                                            const float* __restrict__ b,
                                            u16* __restrict__ hn) {
    int row = blockIdx.x, tid = threadIdx.x;
    const float* hr = h + (long)row * DMM;
    float x0 = hr[tid], x1 = hr[tid + 256], x2 = hr[tid + 512];
    float s = x0 + x1 + x2, sq = x0 * x0 + x1 * x1 + x2 * x2;
    #pragma unroll
    for (int m = 32; m > 0; m >>= 1) {
        s  += __shfl_xor(s,  m, 64);
        sq += __shfl_xor(sq, m, 64);
    }
    __shared__ float ls[4], lq[4];
    int w = tid >> 6;
    if ((tid & 63) == 0) { ls[w] = s; lq[w] = sq; }
    __syncthreads();
    s  = ls[0] + ls[1] + ls[2] + ls[3];
    sq = lq[0] + lq[1] + lq[2] + lq[3];
    float mean = s * (1.0f / DMM);
    float var  = fmaxf(sq * (1.0f / DMM) - mean * mean, 0.0f);
    float rs = rsqrtf(var + 1e-12f);
    u16* hnr = hn + (long)row * DMM;
    hnr[tid]       = f2b((x0 - mean) * rs * g[tid]       + b[tid]);
    hnr[tid + 256] = f2b((x1 - mean) * rs * g[tid + 256] + b[tid + 256]);
    hnr[tid + 512] = f2b((x2 - mean) * rs * g[tid + 512] + b[tid + 512]);
}

// ---------------- GEMM: C[M][N] = A[M][K] @ B  (B given as BT[N][K]) ------
// EPI 0: out = acc + bias              -> bf16 outB
// EPI 1: out = gelu(acc + bias)        -> bf16 outB
// EPI 2: h   = h + (acc + bias) * lam  -> fp32 hio (in place)
template <int EPI>
__global__ __launch_bounds__(256) void gemm_bt(
    const u16* __restrict__ A, const u16* __restrict__ BT,
    const float* __restrict__ bias, u16* __restrict__ outB,
    float* __restrict__ hio, const float* __restrict__ lam,
    int K, int N) {
    __shared__ u16 As[128 * 32];
    __shared__ u16 Bs[128 * 32];
    int tid = threadIdx.x;
    int w = tid >> 6, lane = tid & 63;
    int wr = w >> 1, wc = w & 1;
    int m16 = lane & 15;
    int kq = (lane >> 4) * 8;   // k offset of this lane's 8 elements
    int kq4 = (lane >> 4) * 4;  // C/D row group
    long m0 = (long)blockIdx.x * 128;
    long n0 = (long)blockIdx.y * 128;

    f32x4 acc[4][4] = {};

    int row_a = tid >> 2;          // 0..63
    int col_a = (tid & 3) * 8;     // 0,8,16,24
    const int nsteps = K >> 5;
    for (int ks = 0; ks < nsteps; ++ks) {
        int k0 = ks << 5;
        us8 a0 = *(const us8*)&A[(m0 + row_a) * K + k0 + col_a];
        us8 a1 = *(const us8*)&A[(m0 + 64 + row_a) * K + k0 + col_a];
        us8 b0 = *(const us8*)&BT[(n0 + row_a) * K + k0 + col_a];
        us8 b1 = *(const us8*)&BT[(n0 + 64 + row_a) * K + k0 + col_a];
        __syncthreads();
        *(us8*)&As[row_a * 32 + col_a]        = a0;
        *(us8*)&As[(64 + row_a) * 32 + col_a] = a1;
        *(us8*)&Bs[row_a * 32 + col_a]        = b0;
        *(us8*)&Bs[(64 + row_a) * 32 + col_a] = b1;
        __syncthreads();
        bf16x8 af[4], bf[4];
        #pragma unroll
        for (int i = 0; i < 4; ++i)
            af[i] = *(const bf16x8*)&As[(wr * 64 + i * 16 + m16) * 32 + kq];
        #pragma unroll
        for (int j = 0; j < 4; ++j)
            bf[j] = *(const bf16x8*)&Bs[(wc * 64 + j * 16 + m16) * 32 + kq];
        #pragma unroll
        for (int i = 0; i < 4; ++i)
            #pragma unroll
            for (int j = 0; j < 4; ++j)
                acc[i][j] = __builtin_amdgcn_mfma_f32_16x16x32_bf16(
                    af[i], bf[j], acc[i][j], 0, 0, 0);
    }

    #pragma unroll
    for (int j = 0; j < 4; ++j) {
        long col = n0 + wc * 64 + j * 16 + m16;
        float bv = bias ? bias[col] : 0.0f;
        float lv = (EPI == 2) ? lam[col] : 0.0f;
        #pragma unroll
        for (int i = 0; i < 4; ++i) {
            #pragma unroll
            for (int r = 0; r < 4; ++r) {
                long row = m0 + wr * 64 + i * 16 + kq4 + r;
                float val = acc[i][j][r] + bv;
                long idx = row * N + col;
                if (EPI == 0)      outB[idx] = f2b(val);
                else if (EPI == 1) outB[idx] = f2b(gelu_exact(val));
                else               hio[idx] = hio[idx] + val * lv;
            }
        }
    }
}

// ---------------- relative position bias index ----------------------------
__device__ __forceinline__ int relidx(int q, int k) {
    if (q == 0 && k == 0) return NDD - 1;
    if (k == 0) return NDD - 2;
    if (q == 0) return NDD - 3;
    int a = q - 1, c = k - 1;
    int dh = a / 14 - c / 14 + 13;
    int dw = a % 14 - c % 14 + 13;
    return dh * 27 + dw;
}

// ---------------- attention: per (b,h) block ------------------------------
#define KSTR 66
__global__ __launch_bounds__(256) void attn_k(
    const u16* __restrict__ Q, const u16* __restrict__ K,
    const u16* __restrict__ V, const float* __restrict__ rel,
    u16* __restrict__ ctx) {
    int bh = blockIdx.x;
    int b = bh / NH, hh = bh % NH;
    __shared__ u16 Ks[SQ * KSTR];
    __shared__ u16 Vs[SQ * KSTR];
    __shared__ float ps[4][SQ + 3];
    __shared__ float qs[4][64];
    int tid = threadIdx.x;
    long base = ((long)b * SQ) * DMM + hh * HD;
    for (int idx = tid; idx < SQ * 64; idx += 256) {
        int s1 = idx >> 6, d = idx & 63;
        Ks[s1 * KSTR + d] = K[base + (long)s1 * DMM + d];
        Vs[s1 * KSTR + d] = V[base + (long)s1 * DMM + d];
    }
    __syncthreads();
    int w = tid >> 6, lane = tid & 63;
    const float scale = 0.125f;
    int k3 = (lane < 5) ? (lane + 192) : lane;  // safe row for inactive lanes
    for (int q = w; q < SQ; q += 4) {
        qs[w][lane] = b2f(Q[base + (long)q * DMM + lane]);
        float sc0 = 0, sc1 = 0, sc2 = 0, sc3 = 0;
        #pragma unroll 8
        for (int d = 0; d < 64; ++d) {
            float qd = qs[w][d];
            sc0 += qd * b2f(Ks[lane * KSTR + d]);
            sc1 += qd * b2f(Ks[(lane + 64) * KSTR + d]);
            sc2 += qd * b2f(Ks[(lane + 128) * KSTR + d]);
            sc3 += qd * b2f(Ks[k3 * KSTR + d]);
        }
        sc0 = sc0 * scale + rel[relidx(q, lane) * NH + hh];
        sc1 = sc1 * scale + rel[relidx(q, lane + 64) * NH + hh];
        sc2 = sc2 * scale + rel[relidx(q, lane + 128) * NH + hh];
        sc3 = (lane < 5) ? (sc3 * scale + rel[relidx(q, lane + 192) * NH + hh])
                         : -1e30f;
        float mx = fmaxf(fmaxf(sc0, sc1), fmaxf(sc2, sc3));
        #pragma unroll
        for (int m = 32; m > 0; m >>= 1) mx = fmaxf(mx, __shfl_xor(mx, m, 64));
        float e0 = expf(sc0 - mx), e1 = expf(sc1 - mx), e2 = expf(sc2 - mx);
        float e3 = (lane < 5) ? expf(sc3 - mx) : 0.0f;
        float sum = e0 + e1 + e2 + e3;
        #pragma unroll
        for (int m = 32; m > 0; m >>= 1) sum += __shfl_xor(sum, m, 64);
        float inv = 1.0f / sum;
        ps[w][lane] = e0 * inv;
        ps[w][lane + 64] = e1 * inv;
        ps[w][lane + 128] = e2 * inv;
        if (lane < 5) ps[w][lane + 192] = e3 * inv;
        float acc = 0.0f;
        #pragma unroll 8
        for (int k = 0; k < SQ; ++k)
            acc += ps[w][k] * b2f(Vs[k * KSTR + lane]);
        ctx[base + (long)q * DMM + lane] = f2b(acc);
    }
}

// ---------------- host-side orchestration ---------------------------------
extern "C" void kernel_launch(void* const* d_in, const int* in_sizes, int n_in,
                              void* d_out, int out_size, void* d_ws, size_t ws_size,
                              hipStream_t stream) {
    const float* x    = (const float*)d_in[0];
    const float* cls  = (const float*)d_in[1];
    const float* g1   = (const float*)d_in[2];
    const float* b1   = (const float*)d_in[3];
    const float* Wq   = (const float*)d_in[4];
    const float* bq   = (const float*)d_in[5];
    const float* Wk   = (const float*)d_in[6];
    const float* Wv   = (const float*)d_in[7];
    const float* bv   = (const float*)d_in[8];
    const float* rel  = (const float*)d_in[9];
    const float* Wo   = (const float*)d_in[10];
    const float* bo   = (const float*)d_in[11];
    const float* lam1 = (const float*)d_in[12];
    const float* g2   = (const float*)d_in[13];
    const float* b2   = (const float*)d_in[14];
    const float* Wi   = (const float*)d_in[15];
    const float* bi   = (const float*)d_in[16];
    const float* Wmo  = (const float*)d_in[17];
    const float* bmo  = (const float*)d_in[18];
    const float* lam2 = (const float*)d_in[19];

    char* p = (char*)d_ws;
    auto alloc = [&](size_t bytes) -> void* {
        void* r = (void*)p;
        p += (bytes + 255) & ~(size_t)255;
        return r;
    };
    float* h    = (float*)alloc((size_t)MPAD * DMM * 4);
    u16*   hn   = (u16*)alloc((size_t)MPAD * DMM * 2);   // also reused as ctx
    u16*   qb   = (u16*)alloc((size_t)MPAD * DMM * 2);
    u16*   kb   = (u16*)alloc((size_t)MPAD * DMM * 2);
    u16*   vb   = (u16*)alloc((size_t)MPAD * DMM * 2);
    u16*   ffh  = (u16*)alloc((size_t)MPAD * DFF * 2);
    u16*   WqT  = (u16*)alloc((size_t)DMM * DMM * 2);
    u16*   WkT  = (u16*)alloc((size_t)DMM * DMM * 2);
    u16*   WvT  = (u16*)alloc((size_t)DMM * DMM * 2);
    u16*   WoT  = (u16*)alloc((size_t)DMM * DMM * 2);
    u16*   WiT  = (u16*)alloc((size_t)DMM * DFF * 2);
    u16*   WmoT = (u16*)alloc((size_t)DFF * DMM * 2);
    u16*   ctxb = hn;  // alias: hn dead after QKV GEMMs, live again after Wo GEMM

    patch_k<<<((long)MPAD * DMM + 255) / 256, 256, 0, stream>>>(x, cls, h);

    dim3 tg1(DMM / 32, DMM / 32);
    dim3 tg2(DMM / 32, DFF / 32);   // Wi: K=DMM rows, N=DFF cols
    dim3 tg3(DFF / 32, DMM / 32);   // Wmo: K=DFF rows, N=DMM cols
    dim3 g6(MPAD / 128, DMM / 128);
    dim3 g24(MPAD / 128, DFF / 128);

    for (int i = 0; i < 3; ++i) {
        size_t wofs = (size_t)i * DMM * DMM;
        size_t wofs2 = (size_t)i * DMM * DFF;
        tcast_k<<<tg1, 256, 0, stream>>>(Wq + wofs, WqT, DMM, DMM);
        tcast_k<<<tg1, 256, 0, stream>>>(Wk + wofs, WkT, DMM, DMM);
        tcast_k<<<tg1, 256, 0, stream>>>(Wv + wofs, WvT, DMM, DMM);
        tcast_k<<<tg1, 256, 0, stream>>>(Wo + wofs, WoT, DMM, DMM);
        tcast_k<<<tg2, 256, 0, stream>>>(Wi + wofs2, WiT, DMM, DFF);
        tcast_k<<<tg3, 256, 0, stream>>>(Wmo + wofs2, WmoT, DFF, DMM);

        ln_k<<<MPAD, 256, 0, stream>>>(h, g1 + i * DMM, b1 + i * DMM, hn);
        gemm_bt<0><<<g6, 256, 0, stream>>>(hn, WqT, bq + i * DMM, qb, nullptr, nullptr, DMM, DMM);
        gemm_bt<0><<<g6, 256, 0, stream>>>(hn, WkT, nullptr,      kb, nullptr, nullptr, DMM, DMM);
        gemm_bt<0><<<g6, 256, 0, stream>>>(hn, WvT, bv + i * DMM, vb, nullptr, nullptr, DMM, DMM);
        attn_k<<<BA * NH, 256, 0, stream>>>(qb, kb, vb, rel + (size_t)i * NDD * NH, ctxb);
        gemm_bt<2><<<g6, 256, 0, stream>>>(ctxb, WoT, bo + i * DMM, nullptr, h, lam1 + i * DMM, DMM, DMM);
        ln_k<<<MPAD, 256, 0, stream>>>(h, g2 + i * DMM, b2 + i * DMM, hn);
        gemm_bt<1><<<g24, 256, 0, stream>>>(hn, WiT, bi + i * DFF, ffh, nullptr, nullptr, DMM, DFF);
        gemm_bt<2><<<g6, 256, 0, stream>>>(ffh, WmoT, bmo + i * DMM, nullptr, h, lam2 + i * DMM, DFF, DMM);
    }

    out_k<<<((long)MROWS * DMM + 255) / 256, 256, 0, stream>>>(h, (float*)d_out);
}

// Round 3
// 1687.631 us; speedup vs baseline: 1.9031x; 1.9031x over previous
//
#include <hip/hip_runtime.h>

#define DMM 768
#define DFF 3072
#define NH  12
#define HD  64
#define SQ  197
#define BA  64
#define NDD 732
#define MROWS (BA*SQ)   // 12608
#define MPAD  12672     // 99*128
#define PCOLS 224       // padded k-dim for P (7 x 32)
#define KS2   72        // Ks LDS stride (16B-aligned rows, free 2-way banking)
#define VTS   232       // Vt / P-read stride

typedef unsigned short u16;
typedef __bf16 bf16x8 __attribute__((ext_vector_type(8)));
typedef float  f32x4  __attribute__((ext_vector_type(4)));
typedef unsigned short us8 __attribute__((ext_vector_type(8)));

__device__ __forceinline__ float b2f(u16 u) {
    unsigned v = ((unsigned)u) << 16;
    float f; __builtin_memcpy(&f, &v, 4); return f;
}
__device__ __forceinline__ u16 f2b(float f) {
    unsigned v; __builtin_memcpy(&v, &f, 4);
    unsigned r = v + 0x7FFFu + ((v >> 16) & 1u);
    return (u16)(r >> 16);
}
__device__ __forceinline__ float gelu_exact(float x) {
    return 0.5f * x * (1.0f + erff(x * 0.70710678118654752f));
}
__device__ __forceinline__ void gload16(const u16* g, u16* l) {
    __builtin_amdgcn_global_load_lds(
        (const __attribute__((address_space(1))) unsigned int*)(g),
        (__attribute__((address_space(3))) unsigned int*)(l), 16, 0, 0);
}

// ---------------- patch embed: x[B,14,14,DM] fp32 + cls -> h fp32 ---------
__global__ void patch_k(const float* __restrict__ x, const float* __restrict__ cls,
                        float* __restrict__ h) {
    long idx = (long)blockIdx.x * 256 + threadIdx.x;
    if (idx >= (long)MPAD * DMM) return;
    long r = idx / DMM; int c = (int)(idx % DMM);
    float v = 0.0f;
    if (r < MROWS) {
        int b = (int)(r / SQ), s = (int)(r % SQ);
        v = (s == 0) ? cls[c] : x[((long)b * 196 + (s - 1)) * DMM + c];
    }
    h[idx] = v;
}

// ---------------- final copy fp32 h -> fp32 out ---------------------------
__global__ void out_k(const float* __restrict__ h, float* __restrict__ out) {
    long idx = (long)blockIdx.x * 256 + threadIdx.x;
    if (idx < (long)MROWS * DMM) out[idx] = h[idx];
}

// ------- fused transpose+cast: in fp32 [K][N] -> out bf16 [N][K] ----------
__global__ __launch_bounds__(256) void tcast_k(const float* __restrict__ in,
                                               u16* __restrict__ out,
                                               int Kd, int Nd) {
    __shared__ float t[32][33];
    int k0 = blockIdx.x * 32, n0 = blockIdx.y * 32;
    int tx = threadIdx.x & 31, ty = threadIdx.x >> 5;   // ty 0..7
    #pragma unroll
    for (int i = 0; i < 4; ++i)
        t[tx][ty + 8 * i] = in[(long)(k0 + ty + 8 * i) * Nd + n0 + tx];
    __syncthreads();
    #pragma unroll
    for (int i = 0; i < 4; ++i)
        out[(long)(n0 + ty + 8 * i) * Kd + k0 + tx] = f2b(t[ty + 8 * i][tx]);
}

// ---------------- layernorm: h fp32 -> hn bf16 ----------------------------
__global__ __launch_bounds__(256) void ln_k(const float* __restrict__ h,
                                            const float* __restrict__ g,
                                            const float* __restrict__ b,
                                            u16* __restrict__ hn) {
    int row = blockIdx.x, tid = threadIdx.x;
    const float* hr = h + (long)row * DMM;
    float x0 = hr[tid], x1 = hr[tid + 256], x2 = hr[tid + 512];
    float s = x0 + x1 + x2, sq = x0 * x0 + x1 * x1 + x2 * x2;
    #pragma unroll
    for (int m = 32; m > 0; m >>= 1) {
        s  += __shfl_xor(s,  m, 64);
        sq += __shfl_xor(sq, m, 64);
    }
    __shared__ float ls[4], lq[4];
    int w = tid >> 6;
    if ((tid & 63) == 0) { ls[w] = s; lq[w] = sq; }
    __syncthreads();
    s  = ls[0] + ls[1] + ls[2] + ls[3];
    sq = lq[0] + lq[1] + lq[2] + lq[3];
    float mean = s * (1.0f / DMM);
    float var  = fmaxf(sq * (1.0f / DMM) - mean * mean, 0.0f);
    float rs = rsqrtf(var + 1e-12f);
    u16* hnr = hn + (long)row * DMM;
    hnr[tid]       = f2b((x0 - mean) * rs * g[tid]       + b[tid]);
    hnr[tid + 256] = f2b((x1 - mean) * rs * g[tid + 256] + b[tid + 256]);
    hnr[tid + 512] = f2b((x2 - mean) * rs * g[tid + 512] + b[tid + 512]);
}

// ---------------- GEMM: C[M][N] = A[M][K] @ B  (B given as BT[N][K]) ------
// m97 pattern: global_load_lds width-16 staging, 2-barrier K-loop.
// EPI 0: out = acc + bias              -> bf16 outB
// EPI 1: out = gelu(acc + bias)        -> bf16 outB
// EPI 2: h   = h + (acc + bias) * lam  -> fp32 hio (in place)
template <int EPI>
__global__ __launch_bounds__(256) void gemm_bt(
    const u16* __restrict__ A, const u16* __restrict__ BT,
    const float* __restrict__ bias, u16* __restrict__ outB,
    float* __restrict__ hio, const float* __restrict__ lam,
    int K, int N) {
    __shared__ u16 As[128 * 32];
    __shared__ u16 Bs[128 * 32];
    int tid = threadIdx.x;
    int w = tid >> 6, lane = tid & 63;
    int wr = w >> 1, wc = w & 1;
    int m16 = lane & 15;
    int kq = (lane >> 4) * 8;   // k offset of this lane's 8 elements
    int kq4 = (lane >> 4) * 4;  // C/D row group
    long m0 = (long)blockIdx.x * 128;
    long n0 = (long)blockIdx.y * 128;

    f32x4 acc[4][4] = {};

    int row_a = tid >> 2;          // 0..63
    int col_a = (tid & 3) * 8;     // 0,8,16,24
    const u16* gA0 = &A[(m0 + row_a) * (long)K + col_a];
    const u16* gA1 = &A[(m0 + 64 + row_a) * (long)K + col_a];
    const u16* gB0 = &BT[(n0 + row_a) * (long)K + col_a];
    const u16* gB1 = &BT[(n0 + 64 + row_a) * (long)K + col_a];
    u16* lA0 = As + w * 512;        // wave-uniform base; lane*16B matches tid*16B map
    u16* lA1 = As + 2048 + w * 512;
    u16* lB0 = Bs + w * 512;
    u16* lB1 = Bs + 2048 + w * 512;

    const int nsteps = K >> 5;
    for (int ks = 0; ks < nsteps; ++ks) {
        int k0 = ks << 5;
        __syncthreads();
        gload16(gA0 + k0, lA0);
        gload16(gA1 + k0, lA1);
        gload16(gB0 + k0, lB0);
        gload16(gB1 + k0, lB1);
        __syncthreads();
        bf16x8 af[4], bf[4];
        #pragma unroll
        for (int i = 0; i < 4; ++i)
            af[i] = *(const bf16x8*)&As[(wr * 64 + i * 16 + m16) * 32 + kq];
        #pragma unroll
        for (int j = 0; j < 4; ++j)
            bf[j] = *(const bf16x8*)&Bs[(wc * 64 + j * 16 + m16) * 32 + kq];
        #pragma unroll
        for (int i = 0; i < 4; ++i)
            #pragma unroll
            for (int j = 0; j < 4; ++j)
                acc[i][j] = __builtin_amdgcn_mfma_f32_16x16x32_bf16(
                    af[i], bf[j], acc[i][j], 0, 0, 0);
    }

    #pragma unroll
    for (int j = 0; j < 4; ++j) {
        long col = n0 + wc * 64 + j * 16 + m16;
        float bv = bias ? bias[col] : 0.0f;
        float lv = (EPI == 2) ? lam[col] : 0.0f;
        #pragma unroll
        for (int i = 0; i < 4; ++i) {
            #pragma unroll
            for (int r = 0; r < 4; ++r) {
                long row = m0 + wr * 64 + i * 16 + kq4 + r;
                float val = acc[i][j][r] + bv;
                long idx = row * N + col;
                if (EPI == 0)      outB[idx] = f2b(val);
                else if (EPI == 1) outB[idx] = f2b(gelu_exact(val));
                else               hio[idx] = hio[idx] + val * lv;
            }
        }
    }
}

// ---------------- relative position bias index ----------------------------
__device__ __forceinline__ int relidx(int q, int k) {
    if (q == 0 && k == 0) return NDD - 1;
    if (k == 0) return NDD - 2;
    if (q == 0) return NDD - 3;
    int a = q - 1, c = k - 1;
    int dh = a / 14 - c / 14 + 13;
    int dw = a % 14 - c % 14 + 13;
    return dh * 27 + dw;
}

// -------- precompute bias[h][208][208] fp32 (0 outside valid range) -------
__global__ void bias_k(const float* __restrict__ rel, float* __restrict__ bias) {
    int idx = blockIdx.x * 256 + threadIdx.x;
    if (idx >= NH * 208 * 208) return;
    int hh = idx / (208 * 208);
    int r = (idx / 208) % 208, c = idx % 208;
    float v = 0.0f;
    if (r < SQ && c < SQ) v = rel[relidx(r, c) * NH + hh];
    bias[idx] = v;
}

// -------- attention part 1: S = QK^T * scale + bias, softmax -> P ---------
__global__ __launch_bounds__(256) void attn_qk(
    const u16* __restrict__ Q, const u16* __restrict__ K,
    const float* __restrict__ bias, u16* __restrict__ P) {
    int bh = blockIdx.x;
    int b = bh / NH, hh = bh % NH;
    __shared__ u16 Ks[208 * KS2];
    int tid = threadIdx.x, w = tid >> 6, lane = tid & 63;
    long base = ((long)b * SQ) * DMM + hh * HD;
    u16* Pb = P + (long)bh * 208 * PCOLS;
    // zero P pad cols 208..223 (rows all written below)
    for (int idx = tid; idx < 208 * 16; idx += 256)
        Pb[(idx >> 4) * PCOLS + 208 + (idx & 15)] = 0;
    // stage K rows 0..207 (zeros beyond 196)
    for (int idx = tid; idx < 208 * 8; idx += 256) {
        int row = idx >> 3, dg = (idx & 7) * 8;
        us8 kv = {};
        if (row < SQ) kv = *(const us8*)&K[base + (long)row * DMM + dg];
        *(us8*)&Ks[row * KS2 + dg] = kv;
    }
    __syncthreads();
    int m16 = lane & 15, quad = lane >> 4;
    int kq8 = quad * 8, q4 = quad * 4;
    const float* bh_bias = bias + (long)hh * 208 * 208;
    for (int t = w; t < 13; t += 4) {
        int m0 = t * 16;
        int qrow = m0 + m16; if (qrow > SQ - 1) qrow = SQ - 1;   // clamp pad rows
        bf16x8 a0 = *(const bf16x8*)&Q[base + (long)qrow * DMM + kq8];
        bf16x8 a1 = *(const bf16x8*)&Q[base + (long)qrow * DMM + 32 + kq8];
        f32x4 sc[13];
        #pragma unroll
        for (int n = 0; n < 13; ++n) {
            bf16x8 b0 = *(const bf16x8*)&Ks[(n * 16 + m16) * KS2 + kq8];
            bf16x8 b1 = *(const bf16x8*)&Ks[(n * 16 + m16) * KS2 + 32 + kq8];
            f32x4 z = {};
            z = __builtin_amdgcn_mfma_f32_16x16x32_bf16(a0, b0, z, 0, 0, 0);
            z = __builtin_amdgcn_mfma_f32_16x16x32_bf16(a1, b1, z, 0, 0, 0);
            sc[n] = z;
        }
        float mx[4] = {-3e38f, -3e38f, -3e38f, -3e38f};
        #pragma unroll
        for (int n = 0; n < 13; ++n) {
            int col = n * 16 + m16;
            bool valid = col < SQ;
            #pragma unroll
            for (int r = 0; r < 4; ++r) {
                float v = sc[n][r] * 0.125f + bh_bias[(m0 + q4 + r) * 208 + col];
                v = valid ? v : -3e38f;
                sc[n][r] = v;
                mx[r] = fmaxf(mx[r], v);
            }
        }
        #pragma unroll
        for (int r = 0; r < 4; ++r)
            #pragma unroll
            for (int msk = 1; msk < 16; msk <<= 1)
                mx[r] = fmaxf(mx[r], __shfl_xor(mx[r], msk, 64));
        float sum[4] = {0, 0, 0, 0};
        #pragma unroll
        for (int n = 0; n < 13; ++n)
            #pragma unroll
            for (int r = 0; r < 4; ++r) {
                float e = __expf(sc[n][r] - mx[r]);   // underflows to 0 when masked
                sc[n][r] = e;
                sum[r] += e;
            }
        #pragma unroll
        for (int r = 0; r < 4; ++r)
            #pragma unroll
            for (int msk = 1; msk < 16; msk <<= 1)
                sum[r] += __shfl_xor(sum[r], msk, 64);
        float inv[4];
        #pragma unroll
        for (int r = 0; r < 4; ++r) inv[r] = 1.0f / sum[r];
        #pragma unroll
        for (int n = 0; n < 13; ++n) {
            int col = n * 16 + m16;
            #pragma unroll
            for (int r = 0; r < 4; ++r)
                Pb[(m0 + q4 + r) * PCOLS + col] = f2b(sc[n][r] * inv[r]);
        }
    }
}

// -------- attention part 2: ctx = P @ V -----------------------------------
__global__ __launch_bounds__(256) void attn_pv(
    const u16* __restrict__ P, const u16* __restrict__ V,
    u16* __restrict__ ctx) {
    int bh = blockIdx.x;
    int b = bh / NH, hh = bh % NH;
    __shared__ u16 Vt[64 * VTS];   // Vt[d][k], zeros for k >= 197
    int tid = threadIdx.x, w = tid >> 6, lane = tid & 63;
    long base = ((long)b * SQ) * DMM + hh * HD;
    for (int idx = tid; idx < 224 * 8; idx += 256) {
        int row = idx >> 3, dg = (idx & 7) * 8;   // row = k index
        us8 vv = {};
        if (row < SQ) vv = *(const us8*)&V[base + (long)row * DMM + dg];
        #pragma unroll
        for (int j = 0; j < 8; ++j) Vt[(dg + j) * VTS + row] = vv[j];
    }
    __syncthreads();
    const u16* Pb = P + (long)bh * 208 * PCOLS;
    int m16 = lane & 15, quad = lane >> 4;
    int kq8 = quad * 8, q4 = quad * 4;
    for (int t = w; t < 13; t += 4) {
        int m0 = t * 16;
        f32x4 co[4] = {};
        #pragma unroll
        for (int ks = 0; ks < 7; ++ks) {
            bf16x8 ap = *(const bf16x8*)&Pb[(m0 + m16) * PCOLS + ks * 32 + kq8];
            #pragma unroll
            for (int n = 0; n < 4; ++n) {
                bf16x8 bv = *(const bf16x8*)&Vt[(n * 16 + m16) * VTS + ks * 32 + kq8];
                co[n] = __builtin_amdgcn_mfma_f32_16x16x32_bf16(ap, bv, co[n], 0, 0, 0);
            }
        }
        #pragma unroll
        for (int n = 0; n < 4; ++n) {
            int col = n * 16 + m16;
            #pragma unroll
            for (int r = 0; r < 4; ++r) {
                int qr = m0 + q4 + r;
                if (qr < SQ) ctx[base + (long)qr * DMM + col] = f2b(co[n][r]);
            }
        }
    }
}

// ---------------- host-side orchestration ---------------------------------
extern "C" void kernel_launch(void* const* d_in, const int* in_sizes, int n_in,
                              void* d_out, int out_size, void* d_ws, size_t ws_size,
                              hipStream_t stream) {
    const float* x    = (const float*)d_in[0];
    const float* cls  = (const float*)d_in[1];
    const float* g1   = (const float*)d_in[2];
    const float* b1   = (const float*)d_in[3];
    const float* Wq   = (const float*)d_in[4];
    const float* bq   = (const float*)d_in[5];
    const float* Wk   = (const float*)d_in[6];
    const float* Wv   = (const float*)d_in[7];
    const float* bv   = (const float*)d_in[8];
    const float* rel  = (const float*)d_in[9];
    const float* Wo   = (const float*)d_in[10];
    const float* bo   = (const float*)d_in[11];
    const float* lam1 = (const float*)d_in[12];
    const float* g2   = (const float*)d_in[13];
    const float* b2   = (const float*)d_in[14];
    const float* Wi   = (const float*)d_in[15];
    const float* bi   = (const float*)d_in[16];
    const float* Wmo  = (const float*)d_in[17];
    const float* bmo  = (const float*)d_in[18];
    const float* lam2 = (const float*)d_in[19];

    char* p = (char*)d_ws;
    auto alloc = [&](size_t bytes) -> void* {
        void* r = (void*)p;
        p += (bytes + 255) & ~(size_t)255;
        return r;
    };
    float* h    = (float*)alloc((size_t)MPAD * DMM * 4);
    u16*   hn   = (u16*)alloc((size_t)MPAD * DMM * 2);   // also reused as ctx
    u16*   qb   = (u16*)alloc((size_t)MPAD * DMM * 2);
    u16*   kb   = (u16*)alloc((size_t)MPAD * DMM * 2);
    u16*   vb   = (u16*)alloc((size_t)MPAD * DMM * 2);
    u16*   ffh  = (u16*)alloc((size_t)MPAD * DFF * 2);   // also aliased as P
    u16*   WqT  = (u16*)alloc((size_t)DMM * DMM * 2);
    u16*   WkT  = (u16*)alloc((size_t)DMM * DMM * 2);
    u16*   WvT  = (u16*)alloc((size_t)DMM * DMM * 2);
    u16*   WoT  = (u16*)alloc((size_t)DMM * DMM * 2);
    u16*   WiT  = (u16*)alloc((size_t)DMM * DFF * 2);
    u16*   WmoT = (u16*)alloc((size_t)DFF * DMM * 2);
    float* biasb = (float*)alloc((size_t)NH * 208 * 208 * 4);
    u16*   ctxb = hn;   // alias: hn dead after QKV GEMMs
    u16*   Pbuf = ffh;  // alias: ffh dead during attention (71.6 MB <= 77.9 MB)

    patch_k<<<((long)MPAD * DMM + 255) / 256, 256, 0, stream>>>(x, cls, h);

    dim3 tg1(DMM / 32, DMM / 32);
    dim3 tg2(DMM / 32, DFF / 32);
    dim3 tg3(DFF / 32, DMM / 32);
    dim3 g6(MPAD / 128, DMM / 128);
    dim3 g24(MPAD / 128, DFF / 128);

    for (int i = 0; i < 3; ++i) {
        size_t wofs = (size_t)i * DMM * DMM;
        size_t wofs2 = (size_t)i * DMM * DFF;
        tcast_k<<<tg1, 256, 0, stream>>>(Wq + wofs, WqT, DMM, DMM);
        tcast_k<<<tg1, 256, 0, stream>>>(Wk + wofs, WkT, DMM, DMM);
        tcast_k<<<tg1, 256, 0, stream>>>(Wv + wofs, WvT, DMM, DMM);
        tcast_k<<<tg1, 256, 0, stream>>>(Wo + wofs, WoT, DMM, DMM);
        tcast_k<<<tg2, 256, 0, stream>>>(Wi + wofs2, WiT, DMM, DFF);
        tcast_k<<<tg3, 256, 0, stream>>>(Wmo + wofs2, WmoT, DFF, DMM);
        bias_k<<<(NH * 208 * 208 + 255) / 256, 256, 0, stream>>>(rel + (size_t)i * NDD * NH, biasb);

        ln_k<<<MPAD, 256, 0, stream>>>(h, g1 + i * DMM, b1 + i * DMM, hn);
        gemm_bt<0><<<g6, 256, 0, stream>>>(hn, WqT, bq + i * DMM, qb, nullptr, nullptr, DMM, DMM);
        gemm_bt<0><<<g6, 256, 0, stream>>>(hn, WkT, nullptr,      kb, nullptr, nullptr, DMM, DMM);
        gemm_bt<0><<<g6, 256, 0, stream>>>(hn, WvT, bv + i * DMM, vb, nullptr, nullptr, DMM, DMM);
        attn_qk<<<BA * NH, 256, 0, stream>>>(qb, kb, biasb, Pbuf);
        attn_pv<<<BA * NH, 256, 0, stream>>>(Pbuf, vb, ctxb);
        gemm_bt<2><<<g6, 256, 0, stream>>>(ctxb, WoT, bo + i * DMM, nullptr, h, lam1 + i * DMM, DMM, DMM);
        ln_k<<<MPAD, 256, 0, stream>>>(h, g2 + i * DMM, b2 + i * DMM, hn);
        gemm_bt<1><<<g24, 256, 0, stream>>>(hn, WiT, bi + i * DFF, ffh, nullptr, nullptr, DMM, DFF);
        gemm_bt<2><<<g6, 256, 0, stream>>>(ffh, WmoT, bmo + i * DMM, nullptr, h, lam2 + i * DMM, DFF, DMM);
    }

    out_k<<<((long)MROWS * DMM + 255) / 256, 256, 0, stream>>>(h, (float*)d_out);
}